// Round 12
// baseline (183.989 us; speedup 1.0000x reference)
//
#include <hip/hip_runtime.h>
#include <hip/hip_bf16.h>
#include <stdint.h>

// ---------- types ----------
typedef __attribute__((ext_vector_type(8))) short bf16x8;      // 8 bf16 MFMA frag
typedef __attribute__((ext_vector_type(4))) float f32x4;
typedef __attribute__((ext_vector_type(16))) float f32x16;     // 32x32 MFMA accum
typedef __attribute__((ext_vector_type(4))) unsigned short u16x4;
typedef __attribute__((ext_vector_type(4))) unsigned int u32x4;
typedef __attribute__((ext_vector_type(4))) float float4v;

#define MFMA16(a, b, c) __builtin_amdgcn_mfma_f32_16x16x32_bf16((a), (b), (c), 0, 0, 0)
#define MFMA32(a, b, c) __builtin_amdgcn_mfma_f32_32x32x16_bf16((a), (b), (c), 0, 0, 0)

__device__ __forceinline__ unsigned short f2bf(float f) {
  return __builtin_bit_cast(unsigned short, (__bf16)f);
}
__device__ __forceinline__ uint32_t pk2(float a, float b) {
  return (uint32_t)f2bf(a) | ((uint32_t)f2bf(b) << 16);
}
__device__ __forceinline__ float m3(float a, float b, float c) {
  return fmaxf(fmaxf(a, b), c);                 // v_max3_f32
}

typedef const __attribute__((address_space(1))) void* gptr1_t;
typedef __attribute__((address_space(3))) void* lptr3_t;
__device__ __forceinline__ void gload16(const void* g, void* l) {
  __builtin_amdgcn_global_load_lds((gptr1_t)g, (lptr3_t)l, 16, 0, 0);
}

// ---------- 1) x fp32 -> bf16 ----------
__global__ __launch_bounds__(256) void cvt_x_kernel(const float* __restrict__ in,
                                                    unsigned short* __restrict__ out) {
  int i = blockIdx.x * 256 + threadIdx.x;
  float4v f = ((const float4v*)in)[i];
  u16x4 o;
  o[0] = f2bf(f[0]); o[1] = f2bf(f[1]); o[2] = f2bf(f[2]); o[3] = f2bf(f[3]);
  ((u16x4*)out)[i] = o;
}

// ---------- 2) weight fp32 [K][N] -> bf16 transposed [N][K] ----------
__global__ __launch_bounds__(256) void wt_cvt_kernel(const float* __restrict__ w0,
                                                     const float* __restrict__ w1,
                                                     const float* __restrict__ w2,
                                                     const float* __restrict__ w3,
                                                     unsigned short* __restrict__ out) {
  const float* in = blockIdx.z == 0 ? w0 : blockIdx.z == 1 ? w1 : blockIdx.z == 2 ? w2 : w3;
  unsigned short* o = out + (size_t)blockIdx.z * 1024 * 1024;
  __shared__ float tile[32][33];
  int tx = threadIdx.x & 31, ty = threadIdx.x >> 5;
  int c0 = blockIdx.x * 32, r0 = blockIdx.y * 32;
#pragma unroll
  for (int i = 0; i < 4; i++)
    tile[ty + 8 * i][tx] = in[(size_t)(r0 + ty + 8 * i) * 1024 + c0 + tx];
  __syncthreads();
#pragma unroll
  for (int i = 0; i < 4; i++)
    o[(size_t)(c0 + ty + 8 * i) * 1024 + r0 + tx] = f2bf(tile[tx][ty + 8 * i]);
}

// ---------- 3) GEMM 128x128, BK=32 (m97 structure, verified) ----------
template <bool OUTF32>
__global__ __launch_bounds__(256) void gemm128_kernel(
    const unsigned short* __restrict__ A,
    const unsigned short* __restrict__ B0, const unsigned short* __restrict__ B1,
    const unsigned short* __restrict__ B2,
    void* C0, void* C1, void* C2) {
  constexpr int K = 1024, N = 1024;
  const unsigned short* Bt = blockIdx.z == 0 ? B0 : blockIdx.z == 1 ? B1 : B2;
  void* Cv = blockIdx.z == 0 ? C0 : blockIdx.z == 1 ? C1 : C2;

  __shared__ unsigned short As[128 * 32];
  __shared__ unsigned short Bs[128 * 32];

  const int tid = threadIdx.x;
  const int w = tid >> 6, lane = tid & 63, l15 = lane & 15, l4 = lane >> 4;
  const int wm = w >> 1, wn = w & 1;
  const int m0 = blockIdx.x * 128, n0 = blockIdx.y * 128;

  f32x4 acc[4][4] = {};

  const int srow = w * 32 + (lane >> 2);
  const int scol = (lane & 3) * 8;
  const unsigned short* ga = A + (size_t)(m0 + srow) * K + scol;
  const unsigned short* gb = Bt + (size_t)(n0 + srow) * K + scol;
  char* lA = (char*)As + w * 2048;
  char* lB = (char*)Bs + w * 2048;

  for (int k0 = 0; k0 < K; k0 += 32) {
    __syncthreads();
    gload16(ga + k0, lA);
    gload16(ga + k0 + 16 * K, lA + 1024);
    gload16(gb + k0, lB);
    gload16(gb + k0 + 16 * K, lB + 1024);
    __syncthreads();

    bf16x8 af[4], bfr[4];
#pragma unroll
    for (int mi = 0; mi < 4; mi++)
      af[mi] = *(const bf16x8*)&As[(wm * 64 + mi * 16 + l15) * 32 + 8 * l4];
#pragma unroll
    for (int ni = 0; ni < 4; ni++)
      bfr[ni] = *(const bf16x8*)&Bs[(wn * 64 + ni * 16 + l15) * 32 + 8 * l4];
#pragma unroll
    for (int mi = 0; mi < 4; mi++)
#pragma unroll
      for (int ni = 0; ni < 4; ni++)
        acc[mi][ni] = MFMA16(af[mi], bfr[ni], acc[mi][ni]);
  }

#pragma unroll
  for (int mi = 0; mi < 4; mi++)
#pragma unroll
    for (int ni = 0; ni < 4; ni++)
#pragma unroll
      for (int r = 0; r < 4; r++) {
        int mg = m0 + wm * 64 + mi * 16 + 4 * l4 + r;
        int ng = n0 + wn * 64 + ni * 16 + l15;
        if (OUTF32)
          ((float*)Cv)[(size_t)mg * N + ng] = acc[mi][ni][r];
        else
          ((unsigned short*)Cv)[(size_t)mg * N + ng] = f2bf(acc[mi][ni][r]);
      }
}

// ---------- 3b) GEMM 64x128 f32-out: out-projection ----------
__global__ __launch_bounds__(256) void gemm64_kernel(const unsigned short* __restrict__ A,
                                                     const unsigned short* __restrict__ Bt,
                                                     float* __restrict__ Cv) {
  constexpr int K = 1024, N = 1024;
  __shared__ unsigned short As[64 * 32];
  __shared__ unsigned short Bs[128 * 32];

  const int tid = threadIdx.x;
  const int w = tid >> 6, lane = tid & 63, l15 = lane & 15, l4 = lane >> 4;
  const int wm = w >> 1, wn = w & 1;
  const int m0 = blockIdx.x * 64, n0 = blockIdx.y * 128;

  f32x4 acc[2][4] = {};

  const int arow = w * 16 + (lane >> 2);
  const int brow = w * 32 + (lane >> 2);
  const int scol = (lane & 3) * 8;
  const unsigned short* ga = A + (size_t)(m0 + arow) * K + scol;
  const unsigned short* gb = Bt + (size_t)(n0 + brow) * K + scol;
  char* lA = (char*)As + w * 1024;
  char* lB = (char*)Bs + w * 2048;

  for (int k0 = 0; k0 < K; k0 += 32) {
    __syncthreads();
    gload16(ga + k0, lA);
    gload16(gb + k0, lB);
    gload16(gb + k0 + 16 * K, lB + 1024);
    __syncthreads();

    bf16x8 af[2], bfr[4];
#pragma unroll
    for (int mi = 0; mi < 2; mi++)
      af[mi] = *(const bf16x8*)&As[(wm * 32 + mi * 16 + l15) * 32 + 8 * l4];
#pragma unroll
    for (int ni = 0; ni < 4; ni++)
      bfr[ni] = *(const bf16x8*)&Bs[(wn * 64 + ni * 16 + l15) * 32 + 8 * l4];
#pragma unroll
    for (int mi = 0; mi < 2; mi++)
#pragma unroll
      for (int ni = 0; ni < 4; ni++)
        acc[mi][ni] = MFMA16(af[mi], bfr[ni], acc[mi][ni]);
  }

#pragma unroll
  for (int mi = 0; mi < 2; mi++)
#pragma unroll
    for (int ni = 0; ni < 4; ni++)
#pragma unroll
      for (int r = 0; r < 4; r++) {
        int mg = m0 + wm * 32 + mi * 16 + 4 * l4 + r;
        int ng = n0 + wn * 64 + ni * 16 + l15;
        Cv[(size_t)mg * N + ng] = acc[mi][ni][r];
      }
}

// ---------- 4) causal flash attention: 32x32 MFMA, WAVE-SPECIALIZED streams ----------
// R9's verified 32x32 machinery (QK addressing, mask reg-map, in-register P via
// shfl_xor(32), PV, epilogue transpose — all absmax-passed, no spill) with the
// lane->q mapping fixed: waves 0-1 own q-tile A (qbA, rows w&1*32..+31), waves
// 2-3 own B. No lane touches two streams -> the R4/R6/R7/R8/R10 dual-liveness
// spill trigger is structurally absent. A-waves skip compute for kb>qbA via a
// WAVE-UNIFORM branch (still stage + barrier). Block work = 2(p+1)+2(32-p) = 66
// wave-tiles, uniform; zero dead lanes (R9's flaw fixed).
// Per 16 q-rows per kv-tile: 8 b128 + ~5 bpermute vs R5's ~22 LDS ops; P_lds
// eliminated (LDS 40KB -> 32KB). Staging/XCD decode verbatim R5.
#define QK_KC(KCC, QF)                                                               \
  {                                                                                  \
    const bf16x8 kf0_ = *(const bf16x8*)&Kc[l31 * 64 + (((KCC)*16 + 8 * hf) ^ ksw)]; \
    const bf16x8 kf1_ = *(const bf16x8*)&Kc[(l31 + 32) * 64 + (((KCC)*16 + 8 * hf) ^ ksw)]; \
    s0 = MFMA32(kf0_, QF, s0);                                                       \
    s1 = MFMA32(kf1_, QF, s1);                                                       \
  }

__global__ __launch_bounds__(256, 4) void attn_kernel(const unsigned short* __restrict__ Qb,
                                                      const unsigned short* __restrict__ Kb,
                                                      const unsigned short* __restrict__ Vb,
                                                      unsigned short* __restrict__ Ob) {
  const int bid = blockIdx.x;
  const int xcd = bid & 7, slot = bid >> 3;       // bid%8 = XCD (round-robin dispatch)
  const int hb = xcd * 8 + (slot >> 4);
  const int p = slot & 15;
  const int hh = hb & 15, bb = hb >> 4;

  const int tid = threadIdx.x, w = tid >> 6, lane = tid & 63;
  const int l31 = lane & 31, hf = lane >> 5;

  __shared__ unsigned short K_lds[2][64 * 64];    // [buf][kv][d], col-swizzled
  __shared__ unsigned short Vt_lds[2][64 * 64];   // [buf][d][kv], col-swizzled

  const size_t brow = (size_t)bb * 2048;
  constexpr float C = 0.18033688f;                // 0.125 * log2(e)
  const float NEGINF = -__builtin_inff();
  const int qbA = p, qbB = 31 - p, lastB = qbB;
  const int ksw = 8 * (l31 & 7);

  const bool isA = (w < 2);                       // waves 0-1: stream A; 2-3: stream B
  const int qt = isA ? qbA : qbB;
  const int myLast = isA ? qbA : lastB;           // last kv tile this wave computes
  const int q_g = qt * 64 + (w & 1) * 32 + l31;   // per-lane q row (global)

  // Q fragments (B-operand): k-chunk kc covers d = 16kc + 8hf .. +7
  bf16x8 qf0, qf1, qf2, qf3;
  {
    const unsigned short* qp = Qb + (brow + q_g) * 1024 + hh * 64 + 8 * hf;
    qf0 = *(const bf16x8*)qp;
    qf1 = *(const bf16x8*)(qp + 16);
    qf2 = *(const bf16x8*)(qp + 32);
    qf3 = *(const bf16x8*)(qp + 48);
  }

  f32x16 oO0 = {0,0,0,0,0,0,0,0,0,0,0,0,0,0,0,0};   // O^T rows d 0-31
  f32x16 oO1 = {0,0,0,0,0,0,0,0,0,0,0,0,0,0,0,0};   // O^T rows d 32-63
  float m_run = NEGINF, l_run = 0.0f;

  // K staging: DMA with pre-swizzled global source (verbatim R5)
  const int kcol = 8 * ((lane & 7) ^ ((lane >> 3) & 7));
  const unsigned short* gk = Kb + (brow + 8 * w + (lane >> 3)) * 1024 + hh * 64 + kcol;
  // V staging (verbatim R5)
  const int vr0 = 2 * (tid >> 3);
  const int vsc = (tid & 7) * 8;
  const unsigned short* gv = Vb + (brow + vr0) * 1024 + hh * 64 + vsc;

  auto vt_write = [&](int buf, const bf16x8& v0, const bf16x8& v1) {
#pragma unroll
    for (int j = 0; j < 8; j++) {
      const int d = vsc + j;
      const int msk = 8 * ((d ^ (d >> 3)) & 7);
      uint32_t pkv = (uint32_t)(unsigned short)v0[j] |
                     ((uint32_t)(unsigned short)v1[j] << 16);
      *(uint32_t*)&Vt_lds[buf][d * 64 + (vr0 ^ msk)] = pkv;
    }
  };

  // ---- prologue: stage tile 0 into buf 0 ----
  gload16(gk, (char*)K_lds[0] + w * 1024);
  gload16(gk + 32 * 1024, (char*)K_lds[0] + w * 1024 + 4096);
  {
    bf16x8 v0 = *(const bf16x8*)gv;
    bf16x8 v1 = *(const bf16x8*)(gv + 1024);
    vt_write(0, v0, v1);
  }
  __syncthreads();

  const int vm0 = 8 * ((l31 ^ (l31 >> 3)) & 7);
  const int vm1 = 8 * (((l31 + 32) ^ ((l31 + 32) >> 3)) & 7);

  for (int kb = 0; kb <= lastB; ++kb) {
    const int cur = kb & 1, nxt = cur ^ 1;
    const bool pre = kb < lastB;
    const unsigned short* Kc = K_lds[cur];
    const unsigned short* Vtc = Vt_lds[cur];
    bf16x8 pv0, pv1;
    if (pre) {
      const size_t off = (size_t)(kb + 1) * 64 * 1024;
      gload16(gk + off, (char*)K_lds[nxt] + w * 1024);
      gload16(gk + off + 32 * 1024, (char*)K_lds[nxt] + w * 1024 + 4096);
      pv0 = *(const bf16x8*)(gv + off);
      pv1 = *(const bf16x8*)(gv + off + 1024);
    }

    if (kb <= myLast) {                           // wave-uniform: A-waves skip kb>qbA
      // ---- QK: S^T[kv][q], s0 = kv 0-31, s1 = kv 32-63 ----
      f32x16 s0 = {0,0,0,0,0,0,0,0,0,0,0,0,0,0,0,0};
      f32x16 s1 = {0,0,0,0,0,0,0,0,0,0,0,0,0,0,0,0};
      __builtin_amdgcn_s_setprio(1);
      QK_KC(0, qf0) QK_KC(1, qf1) QK_KC(2, qf2) QK_KC(3, qf3)
      __builtin_amdgcn_s_setprio(0);

      // ---- causal mask on this wave's diagonal tile ----
      if (kb == myLast) {
        const int kv0 = kb * 64;
#pragma unroll
        for (int r = 0; r < 16; r++) {
          const int kvl = (r & 3) + 8 * (r >> 2) + 4 * hf;
          if (kv0 + kvl > q_g) s0[r] = NEGINF;
          if (kv0 + kvl + 32 > q_g) s1[r] = NEGINF;
        }
      }

      // ---- per-lane row max (in-lane tree + 1 cross-half shfl) ----
      float mt;
      {
        float a0 = m3(s0[0], s0[1], s0[2]),  a1 = m3(s0[3], s0[4], s0[5]);
        float a2 = m3(s0[6], s0[7], s0[8]),  a3 = m3(s0[9], s0[10], s0[11]);
        float a4 = m3(s0[12], s0[13], s0[14]);
        float b0 = m3(s1[0], s1[1], s1[2]),  b1 = m3(s1[3], s1[4], s1[5]);
        float b2 = m3(s1[6], s1[7], s1[8]),  b3 = m3(s1[9], s1[10], s1[11]);
        float b4 = m3(s1[12], s1[13], s1[14]);
        float t0 = m3(a0, a1, a2), t1 = m3(a3, a4, s0[15]);
        float t2 = m3(b0, b1, b2), t3 = m3(b3, b4, s1[15]);
        mt = fmaxf(fmaxf(t0, t1), fmaxf(t2, t3));
      }
      mt = fmaxf(mt, __shfl_xor(mt, 32));         // partner lane: same q, other kv half

      // ---- defer-max: decide, apply alpha after exp ----
      float alpha = 1.0f;
      bool doresc = false;
      if (!__all(mt <= m_run + 44.3614f)) {       // 44.3614 = 8 / C
        const float m_new = fmaxf(m_run, mt);
        alpha = __builtin_amdgcn_exp2f((m_run - m_new) * C);
        m_run = m_new;
        doresc = true;
      }
      const float mnc = m_run * C;

      // ---- exp + row-sum + pairwise pack (S dies into pw) ----
      float lt = 0.0f;
      uint32_t pw[16];
#pragma unroll
      for (int rp = 0; rp < 8; rp++) {
        float e0 = __builtin_amdgcn_exp2f(__builtin_fmaf(s0[2 * rp], C, -mnc));
        float e1 = __builtin_amdgcn_exp2f(__builtin_fmaf(s0[2 * rp + 1], C, -mnc));
        lt += e0 + e1;
        pw[rp] = pk2(e0, e1);
        float f0 = __builtin_amdgcn_exp2f(__builtin_fmaf(s1[2 * rp], C, -mnc));
        float f1 = __builtin_amdgcn_exp2f(__builtin_fmaf(s1[2 * rp + 1], C, -mnc));
        lt += f0 + f1;
        pw[8 + rp] = pk2(f0, f1);
      }
      lt += __shfl_xor(lt, 32);
      if (doresc) {
#pragma unroll
        for (int r = 0; r < 16; r++) { oO0[r] *= alpha; oO1[r] *= alpha; }
        l_run *= alpha;
      }
      l_run += lt;

      // ---- P fragments in-register: kv-exchange with partner lane (l^32) ----
      const bool hi = (hf == 1);
      bf16x8 pf0k, pf1k, pf2k, pf3k;
#pragma unroll
      for (int kc = 0; kc < 4; kc++) {
        const int base = 8 * (kc >> 1) + 4 * (kc & 1);
        const uint32_t wA = pw[base], wB = pw[base + 1], wC = pw[base + 2], wD = pw[base + 3];
        const uint32_t sA = hi ? wA : wC;         // send what partner needs
        const uint32_t sB = hi ? wB : wD;
        const uint32_t r1 = __shfl_xor(sA, 32);
        const uint32_t r2 = __shfl_xor(sB, 32);
        u32x4 fw;
        fw[0] = hi ? r1 : wA;
        fw[1] = hi ? r2 : wB;
        fw[2] = hi ? wC : r1;
        fw[3] = hi ? wD : r2;
        const bf16x8 pf = __builtin_bit_cast(bf16x8, fw);
        if (kc == 0) pf0k = pf; else if (kc == 1) pf1k = pf;
        else if (kc == 2) pf2k = pf; else pf3k = pf;
      }

      // ---- PV: O^T += V^T-frag x P-frag ----
      __builtin_amdgcn_s_setprio(1);
#pragma unroll
      for (int kc = 0; kc < 4; kc++) {
        const bf16x8 pf = kc == 0 ? pf0k : kc == 1 ? pf1k : kc == 2 ? pf2k : pf3k;
        const bf16x8 vf0 = *(const bf16x8*)&Vtc[l31 * 64 + ((16 * kc + 8 * hf) ^ vm0)];
        const bf16x8 vf1 = *(const bf16x8*)&Vtc[(l31 + 32) * 64 + ((16 * kc + 8 * hf) ^ vm1)];
        oO0 = MFMA32(vf0, pf, oO0);
        oO1 = MFMA32(vf1, pf, oO1);
      }
      __builtin_amdgcn_s_setprio(0);
    }

    if (pre) vt_write(nxt, pv0, pv1);
    __syncthreads();
  }

  // ---- epilogue: normalize (lane-local), transpose via K_lds, coalesced store ----
  const float li = 1.0f / l_run;
  unsigned short* tb = &K_lds[0][0] + w * 2048;   // per-wave 4KB region [q32][d64]
#pragma unroll
  for (int rp = 0; rp < 8; rp++) {
    const int dd0 = ((2 * rp) & 3) + 8 * (rp >> 1) + 4 * hf;
    *(uint32_t*)&tb[l31 * 64 + (dd0 ^ (8 * (l31 & 7)))] =
        pk2(oO0[2 * rp] * li, oO0[2 * rp + 1] * li);
    const int dd1 = dd0 + 32;
    *(uint32_t*)&tb[l31 * 64 + (dd1 ^ (8 * (l31 & 7)))] =
        pk2(oO1[2 * rp] * li, oO1[2 * rp + 1] * li);
  }
  // same-wave DS ops are in-order; read back coalesced and store
  {
    const int rq = lane >> 1;                     // 0..31
    const int q_out = qt * 64 + (w & 1) * 32 + rq;
    const int dbase = (lane & 1) * 32;
#pragma unroll
    for (int c = 0; c < 4; c++) {
      const int dcol = dbase + 8 * c;
      bf16x8 ov = *(const bf16x8*)&tb[rq * 64 + (dcol ^ (8 * (rq & 7)))];
      *(bf16x8*)&Ob[(brow + q_out) * 1024 + hh * 64 + dcol] = ov;
    }
  }
}

// ---------- launch ----------
extern "C" void kernel_launch(void* const* d_in, const int* in_sizes, int n_in,
                              void* d_out, int out_size, void* d_ws, size_t ws_size,
                              hipStream_t stream) {
  const float* x  = (const float*)d_in[0];
  const float* wq = (const float*)d_in[1];
  const float* wk = (const float*)d_in[2];
  const float* wv = (const float*)d_in[3];
  const float* wo = (const float*)d_in[4];

  char* ws = (char*)d_ws;
  unsigned short* Xb  = (unsigned short*)(ws);
  unsigned short* Wt  = (unsigned short*)(ws + (16u << 20));
  unsigned short* Wqt = Wt;
  unsigned short* Wkt = Wt + (1u << 20);
  unsigned short* Wvt = Wt + (2u << 20);
  unsigned short* Wot = Wt + (3u << 20);
  unsigned short* Qb  = (unsigned short*)(ws + (24u << 20));
  unsigned short* Kb  = (unsigned short*)(ws + (40u << 20));
  unsigned short* Vb  = (unsigned short*)(ws + (56u << 20));
  unsigned short* Ob  = Xb;

  cvt_x_kernel<<<8192, 256, 0, stream>>>(x, Xb);
  wt_cvt_kernel<<<dim3(32, 32, 4), 256, 0, stream>>>(wq, wk, wv, wo, Wt);
  gemm128_kernel<false><<<dim3(64, 8, 3), 256, 0, stream>>>(Xb, Wqt, Wkt, Wvt, Qb, Kb, Vb);
  attn_kernel<<<1024, 256, 0, stream>>>(Qb, Kb, Vb, Ob);
  gemm64_kernel<<<dim3(128, 8), 256, 0, stream>>>(Ob, Wot, (float*)d_out);
}

// Round 13
// 173.805 us; speedup vs baseline: 1.0586x; 1.0586x over previous
//
#include <hip/hip_runtime.h>
#include <hip/hip_bf16.h>
#include <stdint.h>

// ---------- types ----------
typedef __attribute__((ext_vector_type(8))) short bf16x8;     // 8 bf16 (4 VGPRs) MFMA frag
typedef __attribute__((ext_vector_type(4))) float f32x4;      // MFMA accum
typedef __attribute__((ext_vector_type(4))) unsigned short u16x4;
typedef __attribute__((ext_vector_type(4))) float float4v;

#define MFMA16(a, b, c) __builtin_amdgcn_mfma_f32_16x16x32_bf16((a), (b), (c), 0, 0, 0)

// Native f32->bf16 (RTNE); pairs lower to v_cvt_pk_bf16_f32 on gfx950.
__device__ __forceinline__ unsigned short f2bf(float f) {
  return __builtin_bit_cast(unsigned short, (__bf16)f);
}
__device__ __forceinline__ float m3(float a, float b, float c) {
  return fmaxf(fmaxf(a, b), c);                 // clang fuses to v_max3_f32
}

typedef const __attribute__((address_space(1))) void* gptr1_t;
typedef __attribute__((address_space(3))) void* lptr3_t;
__device__ __forceinline__ void gload16(const void* g, void* l) {
  // HW semantics: LDS dest = wave-uniform base + lane*16; global src per-lane.
  __builtin_amdgcn_global_load_lds((gptr1_t)g, (lptr3_t)l, 16, 0, 0);
}

// ---------- 1) x fp32 -> bf16 ----------
__global__ __launch_bounds__(256) void cvt_x_kernel(const float* __restrict__ in,
                                                    unsigned short* __restrict__ out) {
  int i = blockIdx.x * 256 + threadIdx.x;          // exactly n/4 threads launched
  float4v f = ((const float4v*)in)[i];
  u16x4 o;
  o[0] = f2bf(f[0]); o[1] = f2bf(f[1]); o[2] = f2bf(f[2]); o[3] = f2bf(f[3]);
  ((u16x4*)out)[i] = o;
}

// ---------- 2) weight fp32 [K][N] -> bf16 transposed [N][K] ----------
__global__ __launch_bounds__(256) void wt_cvt_kernel(const float* __restrict__ w0,
                                                     const float* __restrict__ w1,
                                                     const float* __restrict__ w2,
                                                     const float* __restrict__ w3,
                                                     unsigned short* __restrict__ out) {
  const float* in = blockIdx.z == 0 ? w0 : blockIdx.z == 1 ? w1 : blockIdx.z == 2 ? w2 : w3;
  unsigned short* o = out + (size_t)blockIdx.z * 1024 * 1024;
  __shared__ float tile[32][33];
  int tx = threadIdx.x & 31, ty = threadIdx.x >> 5;          // 32 x 8
  int c0 = blockIdx.x * 32, r0 = blockIdx.y * 32;
#pragma unroll
  for (int i = 0; i < 4; i++)
    tile[ty + 8 * i][tx] = in[(size_t)(r0 + ty + 8 * i) * 1024 + c0 + tx];
  __syncthreads();
#pragma unroll
  for (int i = 0; i < 4; i++)
    o[(size_t)(c0 + ty + 8 * i) * 1024 + r0 + tx] = f2bf(tile[tx][ty + 8 * i]);
}

// ---------- 3) GEMM 128x128, BK=32 (m97 structure): C = A[M][1024](bf16) @ W ----------
template <bool OUTF32>
__global__ __launch_bounds__(256) void gemm128_kernel(
    const unsigned short* __restrict__ A,
    const unsigned short* __restrict__ B0, const unsigned short* __restrict__ B1,
    const unsigned short* __restrict__ B2,
    void* C0, void* C1, void* C2) {
  constexpr int K = 1024, N = 1024;
  const unsigned short* Bt = blockIdx.z == 0 ? B0 : blockIdx.z == 1 ? B1 : B2;
  void* Cv = blockIdx.z == 0 ? C0 : blockIdx.z == 1 ? C1 : C2;

  __shared__ unsigned short As[128 * 32];
  __shared__ unsigned short Bs[128 * 32];

  const int tid = threadIdx.x;
  const int w = tid >> 6, lane = tid & 63, l15 = lane & 15, l4 = lane >> 4;
  const int wm = w >> 1, wn = w & 1;
  const int m0 = blockIdx.x * 128, n0 = blockIdx.y * 128;

  f32x4 acc[4][4] = {};

  const int srow = w * 32 + (lane >> 2);     // staging row (inst i adds 16)
  const int scol = (lane & 3) * 8;           // bf16 col within BK
  const unsigned short* ga = A + (size_t)(m0 + srow) * K + scol;
  const unsigned short* gb = Bt + (size_t)(n0 + srow) * K + scol;
  char* lA = (char*)As + w * 2048;           // + i*1024 ; HW adds lane*16
  char* lB = (char*)Bs + w * 2048;

  for (int k0 = 0; k0 < K; k0 += 32) {
    __syncthreads();
    gload16(ga + k0, lA);
    gload16(ga + k0 + 16 * K, lA + 1024);
    gload16(gb + k0, lB);
    gload16(gb + k0 + 16 * K, lB + 1024);
    __syncthreads();

    bf16x8 af[4], bfr[4];
#pragma unroll
    for (int mi = 0; mi < 4; mi++)
      af[mi] = *(const bf16x8*)&As[(wm * 64 + mi * 16 + l15) * 32 + 8 * l4];
#pragma unroll
    for (int ni = 0; ni < 4; ni++)
      bfr[ni] = *(const bf16x8*)&Bs[(wn * 64 + ni * 16 + l15) * 32 + 8 * l4];
#pragma unroll
    for (int mi = 0; mi < 4; mi++)
#pragma unroll
      for (int ni = 0; ni < 4; ni++)
        acc[mi][ni] = MFMA16(af[mi], bfr[ni], acc[mi][ni]);
  }

#pragma unroll
  for (int mi = 0; mi < 4; mi++)
#pragma unroll
    for (int ni = 0; ni < 4; ni++)
#pragma unroll
      for (int r = 0; r < 4; r++) {
        int mg = m0 + wm * 64 + mi * 16 + 4 * l4 + r;
        int ng = n0 + wn * 64 + ni * 16 + l15;
        if (OUTF32)
          ((float*)Cv)[(size_t)mg * N + ng] = acc[mi][ni][r];
        else
          ((unsigned short*)Cv)[(size_t)mg * N + ng] = f2bf(acc[mi][ni][r]);
      }
}

// ---------- 3b) GEMM 64x128 f32-out: out-projection (1024 blocks = 4/CU) ----------
__global__ __launch_bounds__(256) void gemm64_kernel(const unsigned short* __restrict__ A,
                                                     const unsigned short* __restrict__ Bt,
                                                     float* __restrict__ Cv) {
  constexpr int K = 1024, N = 1024;
  __shared__ unsigned short As[64 * 32];
  __shared__ unsigned short Bs[128 * 32];

  const int tid = threadIdx.x;
  const int w = tid >> 6, lane = tid & 63, l15 = lane & 15, l4 = lane >> 4;
  const int wm = w >> 1, wn = w & 1;                // wave tile 32x64
  const int m0 = blockIdx.x * 64, n0 = blockIdx.y * 128;

  f32x4 acc[2][4] = {};

  const int arow = w * 16 + (lane >> 2);            // A staging: 16 rows/wave
  const int brow = w * 32 + (lane >> 2);            // B staging: 32 rows/wave (2 insts)
  const int scol = (lane & 3) * 8;
  const unsigned short* ga = A + (size_t)(m0 + arow) * K + scol;
  const unsigned short* gb = Bt + (size_t)(n0 + brow) * K + scol;
  char* lA = (char*)As + w * 1024;
  char* lB = (char*)Bs + w * 2048;

  for (int k0 = 0; k0 < K; k0 += 32) {
    __syncthreads();
    gload16(ga + k0, lA);
    gload16(gb + k0, lB);
    gload16(gb + k0 + 16 * K, lB + 1024);
    __syncthreads();

    bf16x8 af[2], bfr[4];
#pragma unroll
    for (int mi = 0; mi < 2; mi++)
      af[mi] = *(const bf16x8*)&As[(wm * 32 + mi * 16 + l15) * 32 + 8 * l4];
#pragma unroll
    for (int ni = 0; ni < 4; ni++)
      bfr[ni] = *(const bf16x8*)&Bs[(wn * 64 + ni * 16 + l15) * 32 + 8 * l4];
#pragma unroll
    for (int mi = 0; mi < 2; mi++)
#pragma unroll
      for (int ni = 0; ni < 4; ni++)
        acc[mi][ni] = MFMA16(af[mi], bfr[ni], acc[mi][ni]);
  }

#pragma unroll
  for (int mi = 0; mi < 2; mi++)
#pragma unroll
    for (int ni = 0; ni < 4; ni++)
#pragma unroll
      for (int r = 0; r < 4; r++) {
        int mg = m0 + wm * 32 + mi * 16 + 4 * l4 + r;
        int ng = n0 + wn * 64 + ni * 16 + l15;
        Cv[(size_t)mg * N + ng] = acc[mi][ni][r];
      }
}

// ---------- 4) causal flash attention ----------
// R5 verified structure (76us attn, no spill; reproduced twice). Invariants from
// R4/R6/R7/R8/R10 (spills) and R12 (imbalance):
//  - each q-stream completes QK -> softmax -> PV atomically; carrying P fragments
//    across the other stream's softmax (divergent defer-max) spills catastrophically.
//  - the paired A-then-B serial schedule is the balanced causal assignment
//    (33 uniform units/block); wave-specialized parallel streams give blocks a
//    max(p+1,32-p) critical path (R12: +10%).
// Structure: flat grid 1024 XCD-chunked (same-KV blocks -> same XCD L2, KV
// L2-resident); paired q-tiles qbA=p / qbB=31-p; double-buffered K/Vt; ONE
// barrier per KV tile; K via global_load_lds with pre-swizzled global src;
// V reg-staged; ones-MFMA l-sum (l rows == O rows); defer-max (T13); max3-tree
// row max; exp2-domain softmax.
__global__ __launch_bounds__(256, 4) void attn_kernel(const unsigned short* __restrict__ Qb,
                                                      const unsigned short* __restrict__ Kb,
                                                      const unsigned short* __restrict__ Vb,
                                                      unsigned short* __restrict__ Ob) {
  const int bid = blockIdx.x;
  const int xcd = bid & 7, slot = bid >> 3;       // round-robin dispatch: bid%8 = XCD
  const int hb = xcd * 8 + (slot >> 4);           // 8 (h,b) groups per XCD
  const int p = slot & 15;
  const int h = hb & 15, bb = hb >> 4;

  const int tid = threadIdx.x, w = tid >> 6, lane = tid & 63, l15 = lane & 15, l4 = lane >> 4;

  __shared__ unsigned short K_lds[2][64 * 64];    // [buf][kv][d], col-swizzled
  __shared__ unsigned short Vt_lds[2][64 * 64];   // [buf][d][kv], col-swizzled
  __shared__ unsigned short P_lds[4][16 * 64];    // per-wave [q][kv], col-swizzled

  const size_t brow = (size_t)bb * 2048;
  const int qq = w * 16 + l15;                    // in-tile q row (diag mask)
  const int sw = 8 * (l15 & 7);                   // K/P read swizzle (row&7 == l15&7)
  constexpr float C = 0.18033688f;                // 0.125 * log2(e)
  const bf16x8 ones = {0x3F80, 0x3F80, 0x3F80, 0x3F80, 0x3F80, 0x3F80, 0x3F80, 0x3F80};

  const int qbA = p, qbB = 31 - p;
  const int lastB = qbB;

  bf16x8 qfA0, qfA1, qfB0, qfB1;
  {
    const unsigned short* qa = Qb + (brow + qbA * 64 + qq) * 1024 + h * 64 + 8 * l4;
    qfA0 = *(const bf16x8*)qa;
    qfA1 = *(const bf16x8*)(qa + 32);
    const unsigned short* qbp = Qb + (brow + qbB * 64 + qq) * 1024 + h * 64 + 8 * l4;
    qfB0 = *(const bf16x8*)qbp;
    qfB1 = *(const bf16x8*)(qbp + 32);
  }

  f32x4 oA[4] = {}, oB[4] = {};
  f32x4 lA4 = {0.f, 0.f, 0.f, 0.f}, lB4 = {0.f, 0.f, 0.f, 0.f};
  float mrA = -__builtin_inff(), mrB = -__builtin_inff();

  // K staging: DMA with pre-swizzled global source (m173 pattern).
  const int kcol = 8 * ((lane & 7) ^ ((lane >> 3) & 7));
  const unsigned short* gk = Kb + (brow + 8 * w + (lane >> 3)) * 1024 + h * 64 + kcol;
  // V staging: each thread loads kv rows (vr0, vr0+1), d-chunk vsc..+7.
  const int vr0 = 2 * (tid >> 3);                 // 0..62
  const int vsc = (tid & 7) * 8;
  const unsigned short* gv = Vb + (brow + vr0) * 1024 + h * 64 + vsc;

  auto vt_write = [&](int buf, const bf16x8& v0, const bf16x8& v1) {
#pragma unroll
    for (int j = 0; j < 8; j++) {
      const int d = vsc + j;
      const int msk = 8 * ((d ^ (d >> 3)) & 7);
      uint32_t pk = (uint32_t)(unsigned short)v0[j] |
                    ((uint32_t)(unsigned short)v1[j] << 16);
      *(uint32_t*)&Vt_lds[buf][d * 64 + (vr0 ^ msk)] = pk;
    }
  };

  auto tile_compute = [&](const unsigned short* Kc, const unsigned short* Vtc,
                          const bf16x8& q0f, const bf16x8& q1f, f32x4* oacc,
                          float& m_run, f32x4& lacc, bool diag) {
    // S^T = K x Q^T : 8 MFMA
    f32x4 s[4];
    __builtin_amdgcn_s_setprio(1);
#pragma unroll
    for (int sub = 0; sub < 4; ++sub) {
      const unsigned short* kr0 = &Kc[(sub * 16 + l15) * 64 + ((8 * l4) ^ sw)];
      const unsigned short* kr1 = &Kc[(sub * 16 + l15) * 64 + ((32 + 8 * l4) ^ sw)];
      f32x4 z = {0.f, 0.f, 0.f, 0.f};
      z = MFMA16(*(const bf16x8*)kr0, q0f, z);
      z = MFMA16(*(const bf16x8*)kr1, q1f, z);
      s[sub] = z;
    }
    __builtin_amdgcn_s_setprio(0);

    // causal mask only on the diagonal tile
    if (diag) {
#pragma unroll
      for (int sub = 0; sub < 4; ++sub)
#pragma unroll
        for (int r4 = 0; r4 < 4; r4++) {
          const int kv_t = sub * 16 + 4 * l4 + r4;
          s[sub][r4] = (kv_t > qq) ? -__builtin_inff() : s[sub][r4];
        }
    }
    // max3-tree reduce (16 -> 6 -> 2 -> 1), then cross-lane over l4 groups
    const float t0 = m3(s[0][0], s[0][1], s[0][2]);
    const float t1 = m3(s[0][3], s[1][0], s[1][1]);
    const float t2 = m3(s[1][2], s[1][3], s[2][0]);
    const float t3 = m3(s[2][1], s[2][2], s[2][3]);
    const float t4 = m3(s[3][0], s[3][1], s[3][2]);
    float mt = fmaxf(m3(t0, t1, t2), m3(t3, t4, s[3][3]));
    mt = fmaxf(mt, __shfl_xor(mt, 16));
    mt = fmaxf(mt, __shfl_xor(mt, 32));

    // defer-max: only rescale when some row grew by > 8 (log2 units) => P <= 2^8
    if (!__all(mt <= m_run + 44.3614f)) {         // 44.3614 = 8 / C
      const float m_new = fmaxf(m_run, mt);
      const float alpha = __builtin_amdgcn_exp2f((m_run - m_new) * C);
      const float ao0 = __shfl(alpha, 4 * l4 + 0);
      const float ao1 = __shfl(alpha, 4 * l4 + 1);
      const float ao2 = __shfl(alpha, 4 * l4 + 2);
      const float ao3 = __shfl(alpha, 4 * l4 + 3);
#pragma unroll
      for (int d = 0; d < 4; ++d) {
        oacc[d][0] *= ao0; oacc[d][1] *= ao1; oacc[d][2] *= ao2; oacc[d][3] *= ao3;
      }
      lacc[0] *= ao0; lacc[1] *= ao1; lacc[2] *= ao2; lacc[3] *= ao3;
      m_run = m_new;
    }
    const float mnc = m_run * C;

#pragma unroll
    for (int sub = 0; sub < 4; ++sub) {
      u16x4 pw;
#pragma unroll
      for (int r4 = 0; r4 < 4; r4++)
        pw[r4] = f2bf(__builtin_amdgcn_exp2f(__builtin_fmaf(s[sub][r4], C, -mnc)));
      *(u16x4*)&P_lds[w][l15 * 64 + ((sub * 16 + 4 * l4) ^ sw)] = pw;
    }

    // PV: O[q][d] += P[q][kv] V[kv][d]; l[q] += sum_kv P[q][kv] via ones-MFMA
    const bf16x8 pf0 = *(const bf16x8*)&P_lds[w][l15 * 64 + ((8 * l4) ^ sw)];
    const bf16x8 pf1 = *(const bf16x8*)&P_lds[w][l15 * 64 + ((32 + 8 * l4) ^ sw)];
    __builtin_amdgcn_s_setprio(1);
#pragma unroll
    for (int d = 0; d < 4; ++d) {
      const int dd = d * 16 + l15;
      const int vm = 8 * ((dd ^ (dd >> 3)) & 7);
      const unsigned short* vp0 = &Vtc[dd * 64 + ((8 * l4) ^ vm)];
      const unsigned short* vp1 = &Vtc[dd * 64 + ((32 + 8 * l4) ^ vm)];
      oacc[d] = MFMA16(pf0, *(const bf16x8*)vp0, oacc[d]);
      oacc[d] = MFMA16(pf1, *(const bf16x8*)vp1, oacc[d]);
    }
    lacc = MFMA16(pf0, ones, lacc);
    lacc = MFMA16(pf1, ones, lacc);
    __builtin_amdgcn_s_setprio(0);
  };

  // ---- prologue: stage tile 0 into buf 0 ----
  gload16(gk, (char*)K_lds[0] + w * 1024);
  gload16(gk + 32 * 1024, (char*)K_lds[0] + w * 1024 + 4096);
  {
    bf16x8 v0 = *(const bf16x8*)gv;
    bf16x8 v1 = *(const bf16x8*)(gv + 1024);
    vt_write(0, v0, v1);
  }
  __syncthreads();

  // ---- main loop: one barrier per KV tile ----
  for (int kb = 0; kb <= lastB; ++kb) {
    const int cur = kb & 1, nxt = cur ^ 1;
    const bool pre = kb < lastB;
    bf16x8 pv0, pv1;
    if (pre) {
      const size_t off = (size_t)(kb + 1) * 64 * 1024;
      gload16(gk + off, (char*)K_lds[nxt] + w * 1024);
      gload16(gk + off + 32 * 1024, (char*)K_lds[nxt] + w * 1024 + 4096);
      pv0 = *(const bf16x8*)(gv + off);
      pv1 = *(const bf16x8*)(gv + off + 1024);
    }

    if (kb <= qbA)
      tile_compute(K_lds[cur], Vt_lds[cur], qfA0, qfA1, oA, mrA, lA4, kb == qbA);
    tile_compute(K_lds[cur], Vt_lds[cur], qfB0, qfB1, oB, mrB, lB4, kb == lastB);

    if (pre) vt_write(nxt, pv0, pv1);
    __syncthreads();
  }

  // ---- epilogue: normalize + store both q-tiles (l rows == O rows, no shfl) ----
  {
    const float li[4] = {1.0f / lA4[0], 1.0f / lA4[1], 1.0f / lA4[2], 1.0f / lA4[3]};
#pragma unroll
    for (int d = 0; d < 4; ++d)
#pragma unroll
      for (int r4 = 0; r4 < 4; r4++) {
        const size_t orow = brow + qbA * 64 + w * 16 + 4 * l4 + r4;
        Ob[orow * 1024 + h * 64 + d * 16 + l15] = f2bf(oA[d][r4] * li[r4]);
      }
  }
  {
    const float li[4] = {1.0f / lB4[0], 1.0f / lB4[1], 1.0f / lB4[2], 1.0f / lB4[3]};
#pragma unroll
    for (int d = 0; d < 4; ++d)
#pragma unroll
      for (int r4 = 0; r4 < 4; r4++) {
        const size_t orow = brow + qbB * 64 + w * 16 + 4 * l4 + r4;
        Ob[orow * 1024 + h * 64 + d * 16 + l15] = f2bf(oB[d][r4] * li[r4]);
      }
  }
}

// ---------- launch ----------
extern "C" void kernel_launch(void* const* d_in, const int* in_sizes, int n_in,
                              void* d_out, int out_size, void* d_ws, size_t ws_size,
                              hipStream_t stream) {
  const float* x  = (const float*)d_in[0];
  const float* wq = (const float*)d_in[1];
  const float* wk = (const float*)d_in[2];
  const float* wv = (const float*)d_in[3];
  const float* wo = (const float*)d_in[4];

  char* ws = (char*)d_ws;
  // layout (bytes): Xb 16MB | Wt 4x2MB | Q 16MB | K 16MB | V 16MB ; O aliases Xb
  unsigned short* Xb  = (unsigned short*)(ws);
  unsigned short* Wt  = (unsigned short*)(ws + (16u << 20));
  unsigned short* Wqt = Wt;
  unsigned short* Wkt = Wt + (1u << 20);
  unsigned short* Wvt = Wt + (2u << 20);
  unsigned short* Wot = Wt + (3u << 20);
  unsigned short* Qb  = (unsigned short*)(ws + (24u << 20));
  unsigned short* Kb  = (unsigned short*)(ws + (40u << 20));
  unsigned short* Vb  = (unsigned short*)(ws + (56u << 20));
  unsigned short* Ob  = Xb;   // X no longer needed after QKV projection

  cvt_x_kernel<<<8192, 256, 0, stream>>>(x, Xb);                       // 8192*1024 f32 -> bf16
  wt_cvt_kernel<<<dim3(32, 32, 4), 256, 0, stream>>>(wq, wk, wv, wo, Wt);
  gemm128_kernel<false><<<dim3(64, 8, 3), 256, 0, stream>>>(Xb, Wqt, Wkt, Wvt, Qb, Kb, Vb);
  attn_kernel<<<1024, 256, 0, stream>>>(Qb, Kb, Vb, Ob);
  gemm64_kernel<<<dim3(128, 8), 256, 0, stream>>>(Ob, Wot, (float*)d_out);
}

// Round 15
// 173.109 us; speedup vs baseline: 1.0628x; 1.0040x over previous
//
#include <hip/hip_runtime.h>
#include <hip/hip_bf16.h>
#include <stdint.h>

// ---------- types ----------
typedef __attribute__((ext_vector_type(8))) short bf16x8;     // 8 bf16 (4 VGPRs) MFMA frag
typedef __attribute__((ext_vector_type(4))) float f32x4;      // MFMA accum
typedef __attribute__((ext_vector_type(4))) unsigned short u16x4;
typedef __attribute__((ext_vector_type(4))) float float4v;

#define MFMA16(a, b, c) __builtin_amdgcn_mfma_f32_16x16x32_bf16((a), (b), (c), 0, 0, 0)

// Native f32->bf16 (RTNE); pairs lower to v_cvt_pk_bf16_f32 on gfx950.
__device__ __forceinline__ unsigned short f2bf(float f) {
  return __builtin_bit_cast(unsigned short, (__bf16)f);
}
__device__ __forceinline__ float m3(float a, float b, float c) {
  return fmaxf(fmaxf(a, b), c);                 // clang fuses to v_max3_f32
}

typedef const __attribute__((address_space(1))) void* gptr1_t;
typedef __attribute__((address_space(3))) void* lptr3_t;
__device__ __forceinline__ void gload16(const void* g, void* l) {
  // HW semantics: LDS dest = wave-uniform base + lane*16; global src per-lane.
  __builtin_amdgcn_global_load_lds((gptr1_t)g, (lptr3_t)l, 16, 0, 0);
}

// ---------- 1) x fp32 -> bf16 ----------
__global__ __launch_bounds__(256) void cvt_x_kernel(const float* __restrict__ in,
                                                    unsigned short* __restrict__ out) {
  int i = blockIdx.x * 256 + threadIdx.x;          // exactly n/4 threads launched
  float4v f = ((const float4v*)in)[i];
  u16x4 o;
  o[0] = f2bf(f[0]); o[1] = f2bf(f[1]); o[2] = f2bf(f[2]); o[3] = f2bf(f[3]);
  ((u16x4*)out)[i] = o;
}

// ---------- 2) weight fp32 [K][N] -> bf16 transposed [N][K] ----------
__global__ __launch_bounds__(256) void wt_cvt_kernel(const float* __restrict__ w0,
                                                     const float* __restrict__ w1,
                                                     const float* __restrict__ w2,
                                                     const float* __restrict__ w3,
                                                     unsigned short* __restrict__ out) {
  const float* in = blockIdx.z == 0 ? w0 : blockIdx.z == 1 ? w1 : blockIdx.z == 2 ? w2 : w3;
  unsigned short* o = out + (size_t)blockIdx.z * 1024 * 1024;
  __shared__ float tile[32][33];
  int tx = threadIdx.x & 31, ty = threadIdx.x >> 5;          // 32 x 8
  int c0 = blockIdx.x * 32, r0 = blockIdx.y * 32;
#pragma unroll
  for (int i = 0; i < 4; i++)
    tile[ty + 8 * i][tx] = in[(size_t)(r0 + ty + 8 * i) * 1024 + c0 + tx];
  __syncthreads();
#pragma unroll
  for (int i = 0; i < 4; i++)
    o[(size_t)(c0 + ty + 8 * i) * 1024 + r0 + tx] = f2bf(tile[tx][ty + 8 * i]);
}

// ---------- 3) GEMM 128x128, BK=32 (m97 structure): C = A[M][1024](bf16) @ W ----------
template <bool OUTF32>
__global__ __launch_bounds__(256) void gemm128_kernel(
    const unsigned short* __restrict__ A,
    const unsigned short* __restrict__ B0, const unsigned short* __restrict__ B1,
    const unsigned short* __restrict__ B2,
    void* C0, void* C1, void* C2) {
  constexpr int K = 1024, N = 1024;
  const unsigned short* Bt = blockIdx.z == 0 ? B0 : blockIdx.z == 1 ? B1 : B2;
  void* Cv = blockIdx.z == 0 ? C0 : blockIdx.z == 1 ? C1 : C2;

  __shared__ unsigned short As[128 * 32];
  __shared__ unsigned short Bs[128 * 32];

  const int tid = threadIdx.x;
  const int w = tid >> 6, lane = tid & 63, l15 = lane & 15, l4 = lane >> 4;
  const int wm = w >> 1, wn = w & 1;
  const int m0 = blockIdx.x * 128, n0 = blockIdx.y * 128;

  f32x4 acc[4][4] = {};

  const int srow = w * 32 + (lane >> 2);     // staging row (inst i adds 16)
  const int scol = (lane & 3) * 8;           // bf16 col within BK
  const unsigned short* ga = A + (size_t)(m0 + srow) * K + scol;
  const unsigned short* gb = Bt + (size_t)(n0 + srow) * K + scol;
  char* lA = (char*)As + w * 2048;           // + i*1024 ; HW adds lane*16
  char* lB = (char*)Bs + w * 2048;

  for (int k0 = 0; k0 < K; k0 += 32) {
    __syncthreads();
    gload16(ga + k0, lA);
    gload16(ga + k0 + 16 * K, lA + 1024);
    gload16(gb + k0, lB);
    gload16(gb + k0 + 16 * K, lB + 1024);
    __syncthreads();

    bf16x8 af[4], bfr[4];
#pragma unroll
    for (int mi = 0; mi < 4; mi++)
      af[mi] = *(const bf16x8*)&As[(wm * 64 + mi * 16 + l15) * 32 + 8 * l4];
#pragma unroll
    for (int ni = 0; ni < 4; ni++)
      bfr[ni] = *(const bf16x8*)&Bs[(wn * 64 + ni * 16 + l15) * 32 + 8 * l4];
#pragma unroll
    for (int mi = 0; mi < 4; mi++)
#pragma unroll
      for (int ni = 0; ni < 4; ni++)
        acc[mi][ni] = MFMA16(af[mi], bfr[ni], acc[mi][ni]);
  }

#pragma unroll
  for (int mi = 0; mi < 4; mi++)
#pragma unroll
    for (int ni = 0; ni < 4; ni++)
#pragma unroll
      for (int r = 0; r < 4; r++) {
        int mg = m0 + wm * 64 + mi * 16 + 4 * l4 + r;
        int ng = n0 + wn * 64 + ni * 16 + l15;
        if (OUTF32)
          ((float*)Cv)[(size_t)mg * N + ng] = acc[mi][ni][r];
        else
          ((unsigned short*)Cv)[(size_t)mg * N + ng] = f2bf(acc[mi][ni][r]);
      }
}

// ---------- 3b) GEMM 64x128 f32-out: out-projection (1024 blocks = 4/CU) ----------
__global__ __launch_bounds__(256) void gemm64_kernel(const unsigned short* __restrict__ A,
                                                     const unsigned short* __restrict__ Bt,
                                                     float* __restrict__ Cv) {
  constexpr int K = 1024, N = 1024;
  __shared__ unsigned short As[64 * 32];
  __shared__ unsigned short Bs[128 * 32];

  const int tid = threadIdx.x;
  const int w = tid >> 6, lane = tid & 63, l15 = lane & 15, l4 = lane >> 4;
  const int wm = w >> 1, wn = w & 1;                // wave tile 32x64
  const int m0 = blockIdx.x * 64, n0 = blockIdx.y * 128;

  f32x4 acc[2][4] = {};

  const int arow = w * 16 + (lane >> 2);            // A staging: 16 rows/wave
  const int brow = w * 32 + (lane >> 2);            // B staging: 32 rows/wave (2 insts)
  const int scol = (lane & 3) * 8;
  const unsigned short* ga = A + (size_t)(m0 + arow) * K + scol;
  const unsigned short* gb = Bt + (size_t)(n0 + brow) * K + scol;
  char* lA = (char*)As + w * 1024;
  char* lB = (char*)Bs + w * 2048;

  for (int k0 = 0; k0 < K; k0 += 32) {
    __syncthreads();
    gload16(ga + k0, lA);
    gload16(gb + k0, lB);
    gload16(gb + k0 + 16 * K, lB + 1024);
    __syncthreads();

    bf16x8 af[2], bfr[4];
#pragma unroll
    for (int mi = 0; mi < 2; mi++)
      af[mi] = *(const bf16x8*)&As[(wm * 32 + mi * 16 + l15) * 32 + 8 * l4];
#pragma unroll
    for (int ni = 0; ni < 4; ni++)
      bfr[ni] = *(const bf16x8*)&Bs[(wn * 64 + ni * 16 + l15) * 32 + 8 * l4];
#pragma unroll
    for (int mi = 0; mi < 2; mi++)
#pragma unroll
      for (int ni = 0; ni < 4; ni++)
        acc[mi][ni] = MFMA16(af[mi], bfr[ni], acc[mi][ni]);
  }

#pragma unroll
  for (int mi = 0; mi < 2; mi++)
#pragma unroll
    for (int ni = 0; ni < 4; ni++)
#pragma unroll
      for (int r = 0; r < 4; r++) {
        int mg = m0 + wm * 32 + mi * 16 + 4 * l4 + r;
        int ng = n0 + wn * 64 + ni * 16 + l15;
        Cv[(size_t)mg * N + ng] = acc[mi][ni][r];
      }
}

// ---------- 4) causal flash attention ----------
// R5 verified structure (76us attn, no spill; reproduced 3x at 173.8-174.3us
// total). Final form. Invariants established over this session:
//  - each q-stream completes QK -> softmax -> PV atomically; carrying P fragments
//    across the other stream's softmax (divergent defer-max) spills catastrophically
//    (R4/R6/R7/R8/R10: five source forms, same failure).
//  - paired A-then-B serial schedule is the balanced causal assignment (33 uniform
//    units/block); wave-parallel streams create a max(p+1,32-p) critical path
//    (R12: +10%).
//  - shfl_xor->permlane substitution requires ISA semantics not verifiable here
//    (R14: absmax NaN; reverted).
// Structure: flat grid 1024 XCD-chunked (same-KV blocks -> same XCD L2, KV
// L2-resident, FETCH 26MB); paired q-tiles qbA=p / qbB=31-p; double-buffered
// K/Vt; ONE barrier per KV tile; K via global_load_lds with pre-swizzled global
// src (m173); V reg-staged packed-b32 swizzled; ones-MFMA l-sum (l rows == O
// rows, no epilogue shfl); defer-max (T13); max3-tree row max; exp2-domain
// softmax; all LDS access XOR-swizzled conflict-minimal.
__global__ __launch_bounds__(256, 4) void attn_kernel(const unsigned short* __restrict__ Qb,
                                                      const unsigned short* __restrict__ Kb,
                                                      const unsigned short* __restrict__ Vb,
                                                      unsigned short* __restrict__ Ob) {
  const int bid = blockIdx.x;
  const int xcd = bid & 7, slot = bid >> 3;       // round-robin dispatch: bid%8 = XCD
  const int hb = xcd * 8 + (slot >> 4);           // 8 (h,b) groups per XCD
  const int p = slot & 15;
  const int h = hb & 15, bb = hb >> 4;

  const int tid = threadIdx.x, w = tid >> 6, lane = tid & 63, l15 = lane & 15, l4 = lane >> 4;

  __shared__ unsigned short K_lds[2][64 * 64];    // [buf][kv][d], col-swizzled
  __shared__ unsigned short Vt_lds[2][64 * 64];   // [buf][d][kv], col-swizzled
  __shared__ unsigned short P_lds[4][16 * 64];    // per-wave [q][kv], col-swizzled

  const size_t brow = (size_t)bb * 2048;
  const int qq = w * 16 + l15;                    // in-tile q row (diag mask)
  const int sw = 8 * (l15 & 7);                   // K/P read swizzle (row&7 == l15&7)
  constexpr float C = 0.18033688f;                // 0.125 * log2(e)
  const bf16x8 ones = {0x3F80, 0x3F80, 0x3F80, 0x3F80, 0x3F80, 0x3F80, 0x3F80, 0x3F80};

  const int qbA = p, qbB = 31 - p;
  const int lastB = qbB;

  bf16x8 qfA0, qfA1, qfB0, qfB1;
  {
    const unsigned short* qa = Qb + (brow + qbA * 64 + qq) * 1024 + h * 64 + 8 * l4;
    qfA0 = *(const bf16x8*)qa;
    qfA1 = *(const bf16x8*)(qa + 32);
    const unsigned short* qbp = Qb + (brow + qbB * 64 + qq) * 1024 + h * 64 + 8 * l4;
    qfB0 = *(const bf16x8*)qbp;
    qfB1 = *(const bf16x8*)(qbp + 32);
  }

  f32x4 oA[4] = {}, oB[4] = {};
  f32x4 lA4 = {0.f, 0.f, 0.f, 0.f}, lB4 = {0.f, 0.f, 0.f, 0.f};
  float mrA = -__builtin_inff(), mrB = -__builtin_inff();

  // K staging: DMA with pre-swizzled global source (m173 pattern).
  const int kcol = 8 * ((lane & 7) ^ ((lane >> 3) & 7));
  const unsigned short* gk = Kb + (brow + 8 * w + (lane >> 3)) * 1024 + h * 64 + kcol;
  // V staging: each thread loads kv rows (vr0, vr0+1), d-chunk vsc..+7.
  const int vr0 = 2 * (tid >> 3);                 // 0..62
  const int vsc = (tid & 7) * 8;
  const unsigned short* gv = Vb + (brow + vr0) * 1024 + h * 64 + vsc;

  auto vt_write = [&](int buf, const bf16x8& v0, const bf16x8& v1) {
#pragma unroll
    for (int j = 0; j < 8; j++) {
      const int d = vsc + j;
      const int msk = 8 * ((d ^ (d >> 3)) & 7);
      uint32_t pk = (uint32_t)(unsigned short)v0[j] |
                    ((uint32_t)(unsigned short)v1[j] << 16);
      *(uint32_t*)&Vt_lds[buf][d * 64 + (vr0 ^ msk)] = pk;
    }
  };

  auto tile_compute = [&](const unsigned short* Kc, const unsigned short* Vtc,
                          const bf16x8& q0f, const bf16x8& q1f, f32x4* oacc,
                          float& m_run, f32x4& lacc, bool diag) {
    // S^T = K x Q^T : 8 MFMA
    f32x4 s[4];
    __builtin_amdgcn_s_setprio(1);
#pragma unroll
    for (int sub = 0; sub < 4; ++sub) {
      const unsigned short* kr0 = &Kc[(sub * 16 + l15) * 64 + ((8 * l4) ^ sw)];
      const unsigned short* kr1 = &Kc[(sub * 16 + l15) * 64 + ((32 + 8 * l4) ^ sw)];
      f32x4 z = {0.f, 0.f, 0.f, 0.f};
      z = MFMA16(*(const bf16x8*)kr0, q0f, z);
      z = MFMA16(*(const bf16x8*)kr1, q1f, z);
      s[sub] = z;
    }
    __builtin_amdgcn_s_setprio(0);

    // causal mask only on the diagonal tile
    if (diag) {
#pragma unroll
      for (int sub = 0; sub < 4; ++sub)
#pragma unroll
        for (int r4 = 0; r4 < 4; r4++) {
          const int kv_t = sub * 16 + 4 * l4 + r4;
          s[sub][r4] = (kv_t > qq) ? -__builtin_inff() : s[sub][r4];
        }
    }
    // max3-tree reduce (16 -> 6 -> 2 -> 1), then cross-lane over l4 groups
    const float t0 = m3(s[0][0], s[0][1], s[0][2]);
    const float t1 = m3(s[0][3], s[1][0], s[1][1]);
    const float t2 = m3(s[1][2], s[1][3], s[2][0]);
    const float t3 = m3(s[2][1], s[2][2], s[2][3]);
    const float t4 = m3(s[3][0], s[3][1], s[3][2]);
    float mt = fmaxf(m3(t0, t1, t2), m3(t3, t4, s[3][3]));
    mt = fmaxf(mt, __shfl_xor(mt, 16));
    mt = fmaxf(mt, __shfl_xor(mt, 32));

    // defer-max: only rescale when some row grew by > 8 (log2 units) => P <= 2^8
    if (!__all(mt <= m_run + 44.3614f)) {         // 44.3614 = 8 / C
      const float m_new = fmaxf(m_run, mt);
      const float alpha = __builtin_amdgcn_exp2f((m_run - m_new) * C);
      const float ao0 = __shfl(alpha, 4 * l4 + 0);
      const float ao1 = __shfl(alpha, 4 * l4 + 1);
      const float ao2 = __shfl(alpha, 4 * l4 + 2);
      const float ao3 = __shfl(alpha, 4 * l4 + 3);
#pragma unroll
      for (int d = 0; d < 4; ++d) {
        oacc[d][0] *= ao0; oacc[d][1] *= ao1; oacc[d][2] *= ao2; oacc[d][3] *= ao3;
      }
      lacc[0] *= ao0; lacc[1] *= ao1; lacc[2] *= ao2; lacc[3] *= ao3;
      m_run = m_new;
    }
    const float mnc = m_run * C;

#pragma unroll
    for (int sub = 0; sub < 4; ++sub) {
      u16x4 pw;
#pragma unroll
      for (int r4 = 0; r4 < 4; r4++)
        pw[r4] = f2bf(__builtin_amdgcn_exp2f(__builtin_fmaf(s[sub][r4], C, -mnc)));
      *(u16x4*)&P_lds[w][l15 * 64 + ((sub * 16 + 4 * l4) ^ sw)] = pw;
    }

    // PV: O[q][d] += P[q][kv] V[kv][d]; l[q] += sum_kv P[q][kv] via ones-MFMA
    const bf16x8 pf0 = *(const bf16x8*)&P_lds[w][l15 * 64 + ((8 * l4) ^ sw)];
    const bf16x8 pf1 = *(const bf16x8*)&P_lds[w][l15 * 64 + ((32 + 8 * l4) ^ sw)];
    __builtin_amdgcn_s_setprio(1);
#pragma unroll
    for (int d = 0; d < 4; ++d) {
      const int dd = d * 16 + l15;
      const int vm = 8 * ((dd ^ (dd >> 3)) & 7);
      const unsigned short* vp0 = &Vtc[dd * 64 + ((8 * l4) ^ vm)];
      const unsigned short* vp1 = &Vtc[dd * 64 + ((32 + 8 * l4) ^ vm)];
      oacc[d] = MFMA16(pf0, *(const bf16x8*)vp0, oacc[d]);
      oacc[d] = MFMA16(pf1, *(const bf16x8*)vp1, oacc[d]);
    }
    lacc = MFMA16(pf0, ones, lacc);
    lacc = MFMA16(pf1, ones, lacc);
    __builtin_amdgcn_s_setprio(0);
  };

  // ---- prologue: stage tile 0 into buf 0 ----
  gload16(gk, (char*)K_lds[0] + w * 1024);
  gload16(gk + 32 * 1024, (char*)K_lds[0] + w * 1024 + 4096);
  {
    bf16x8 v0 = *(const bf16x8*)gv;
    bf16x8 v1 = *(const bf16x8*)(gv + 1024);
    vt_write(0, v0, v1);
  }
  __syncthreads();

  // ---- main loop: one barrier per KV tile ----
  for (int kb = 0; kb <= lastB; ++kb) {
    const int cur = kb & 1, nxt = cur ^ 1;
    const bool pre = kb < lastB;
    bf16x8 pv0, pv1;
    if (pre) {
      const size_t off = (size_t)(kb + 1) * 64 * 1024;
      gload16(gk + off, (char*)K_lds[nxt] + w * 1024);
      gload16(gk + off + 32 * 1024, (char*)K_lds[nxt] + w * 1024 + 4096);
      pv0 = *(const bf16x8*)(gv + off);
      pv1 = *(const bf16x8*)(gv + off + 1024);
    }

    if (kb <= qbA)
      tile_compute(K_lds[cur], Vt_lds[cur], qfA0, qfA1, oA, mrA, lA4, kb == qbA);
    tile_compute(K_lds[cur], Vt_lds[cur], qfB0, qfB1, oB, mrB, lB4, kb == lastB);

    if (pre) vt_write(nxt, pv0, pv1);
    __syncthreads();
  }

  // ---- epilogue: normalize + store both q-tiles (l rows == O rows, no shfl) ----
  {
    const float li[4] = {1.0f / lA4[0], 1.0f / lA4[1], 1.0f / lA4[2], 1.0f / lA4[3]};
#pragma unroll
    for (int d = 0; d < 4; ++d)
#pragma unroll
      for (int r4 = 0; r4 < 4; r4++) {
        const size_t orow = brow + qbA * 64 + w * 16 + 4 * l4 + r4;
        Ob[orow * 1024 + h * 64 + d * 16 + l15] = f2bf(oA[d][r4] * li[r4]);
      }
  }
  {
    const float li[4] = {1.0f / lB4[0], 1.0f / lB4[1], 1.0f / lB4[2], 1.0f / lB4[3]};
#pragma unroll
    for (int d = 0; d < 4; ++d)
#pragma unroll
      for (int r4 = 0; r4 < 4; r4++) {
        const size_t orow = brow + qbB * 64 + w * 16 + 4 * l4 + r4;
        Ob[orow * 1024 + h * 64 + d * 16 + l15] = f2bf(oB[d][r4] * li[r4]);
      }
  }
}

// ---------- launch ----------
extern "C" void kernel_launch(void* const* d_in, const int* in_sizes, int n_in,
                              void* d_out, int out_size, void* d_ws, size_t ws_size,
                              hipStream_t stream) {
  const float* x  = (const float*)d_in[0];
  const float* wq = (const float*)d_in[1];
  const float* wk = (const float*)d_in[2];
  const float* wv = (const float*)d_in[3];
  const float* wo = (const float*)d_in[4];

  char* ws = (char*)d_ws;
  // layout (bytes): Xb 16MB | Wt 4x2MB | Q 16MB | K 16MB | V 16MB ; O aliases Xb
  unsigned short* Xb  = (unsigned short*)(ws);
  unsigned short* Wt  = (unsigned short*)(ws + (16u << 20));
  unsigned short* Wqt = Wt;
  unsigned short* Wkt = Wt + (1u << 20);
  unsigned short* Wvt = Wt + (2u << 20);
  unsigned short* Wot = Wt + (3u << 20);
  unsigned short* Qb  = (unsigned short*)(ws + (24u << 20));
  unsigned short* Kb  = (unsigned short*)(ws + (40u << 20));
  unsigned short* Vb  = (unsigned short*)(ws + (56u << 20));
  unsigned short* Ob  = Xb;   // X no longer needed after QKV projection

  cvt_x_kernel<<<8192, 256, 0, stream>>>(x, Xb);                       // 8192*1024 f32 -> bf16
  wt_cvt_kernel<<<dim3(32, 32, 4), 256, 0, stream>>>(wq, wk, wv, wo, Wt);
  gemm128_kernel<false><<<dim3(64, 8, 3), 256, 0, stream>>>(Xb, Wqt, Wkt, Wvt, Qb, Kb, Vb);
  attn_kernel<<<1024, 256, 0, stream>>>(Qb, Kb, Vb, Ob);
  gemm64_kernel<<<dim3(128, 8), 256, 0, stream>>>(Ob, Wot, (float*)d_out);
}